// Round 4
// baseline (514.746 us; speedup 1.0000x reference)
//
#include <hip/hip_runtime.h>
#include <float.h>
#include <stdint.h>

#define NUM_CELLS 2048
#define CELL_DIM  256
#define N_STATES  131072

typedef _Float16 half8 __attribute__((ext_vector_type(8)));
typedef float    f32x4 __attribute__((ext_vector_type(4)));

// Stage-1 (1-pass fp16) sim-difference noise sigma ~4.5e-3; M1 = 22 sigma.
#define M1 0.10f
// Stage-2 (fp16x2 3-pass) noise sigma ~1.5e-5; M2 = 0.0008 ~ 50 sigma.
// Rows with gap in [M2, 0.004] are decided identically by stage-2 and exact
// fp32 (50+ sigma margin), so lowering M2 only shrinks the rescue3 set.
#define M2 0.0008f
#define CAP1 32768
#define CAP2 4096

// ws layout (bytes). ws_size >= 3145728 confirmed (rounds 2-3 ran this path).
#define WS_C1 0
#define WS_C2 4
#define WS_L1 1024
#define WS_L2 (WS_L1 + 4 * CAP1)                    // 132096
#define WS_PH 262144
#define WS_PL (WS_PH + 1048576)
// 128 KB slack after pl: the B-stream rotation's tail prefetch overruns by
// up to ~80 KB (reads are consumed never used) — must be mapped.
#define WS_NEEDED (WS_PL + 1048576 + 131072)        // 2490368

// ---------------------------------------------------------------------------
// Prep: p fp32 -> B-fragment-order fp16 hi + (lo*2048) arrays; zero counters.
// Frag order (16x16x32 f16 B): half8 index d = (ct*8 + kf)*64 + l, where
// cell = ct*16 + (l&15), k = kf*32 + (l>>4)*8 + j.
// ---------------------------------------------------------------------------
__global__ void prep_p(const float* __restrict__ p, _Float16* __restrict__ ph,
                       _Float16* __restrict__ pl, int* __restrict__ c1,
                       int* __restrict__ c2) {
    int d = blockIdx.x * 256 + threadIdx.x;   // 65536 dests
    if (d == 0) { *c1 = 0; *c2 = 0; }
    int l = d & 63, kf = (d >> 6) & 7, ct = d >> 9;
    int cell = ct * 16 + (l & 15);
    int k0 = kf * 32 + (l >> 4) * 8;
    const float* s = p + cell * 256 + k0;
    float4 a = *(const float4*)s, b = *(const float4*)(s + 4);
    float v[8] = {a.x, a.y, a.z, a.w, b.x, b.y, b.z, b.w};
    half8 h, lo;
#pragma unroll
    for (int j = 0; j < 8; ++j) {
        _Float16 hi = (_Float16)v[j];
        h[j] = hi;
        lo[j] = (_Float16)((v[j] - (float)hi) * 2048.0f);  // scaled: no fp16 denorms
    }
    *(half8*)(ph + (size_t)d * 8) = h;
    *(half8*)(pl + (size_t)d * 8) = lo;
}

// ---------------------------------------------------------------------------
// Kernel A: 1-pass fp16 MFMA GEMM, barrier-free K-loop.
// Block = 128 rows; 512 thr = 8 waves (wr 0..1 row half x wc 0..3 col group).
// A-frags (64 rows x K=256) in 128 VGPRs. B streamed global->VGPR from
// frag-order ph (L2-resident) with depth-4 rotation (vmcnt(3)-style pipeline).
// LDS used only for the one-time x->fp16 conversion and the final reduce.
// ---------------------------------------------------------------------------
__launch_bounds__(512, 2)
__global__ void pc_gemm1(const float* __restrict__ x, const _Float16* __restrict__ ph,
                         int* __restrict__ out, int* __restrict__ c1,
                         int* __restrict__ l1) {
    __shared__ _Float16 smem[32768];   // 64 KB: x-frag staging, then reduce buf

    const int tid = threadIdx.x;
    const int l = tid & 63;
    const int w = tid >> 6;
    const int wr = w >> 2, wc = w & 3;

    // Phase 1: x fp32 -> fp16 A-frag order in LDS (once per block).
    const float* xg = x + (size_t)blockIdx.x * (128 * CELL_DIM);
#pragma unroll
    for (int i = 0; i < 8; ++i) {
        int d = tid + i * 512;            // 4096 half8 dests
        int dl = d & 63, kf = (d >> 6) & 7, rt = d >> 9;
        int row = rt * 16 + (dl & 15);
        int k0 = kf * 32 + (dl >> 4) * 8;
        const float* s = xg + row * 256 + k0;
        float4 a = *(const float4*)s, b = *(const float4*)(s + 4);
        half8 h;
        h[0] = (_Float16)a.x; h[1] = (_Float16)a.y;
        h[2] = (_Float16)a.z; h[3] = (_Float16)a.w;
        h[4] = (_Float16)b.x; h[5] = (_Float16)b.y;
        h[6] = (_Float16)b.z; h[7] = (_Float16)b.w;
        *(half8*)(smem + d * 8) = h;
    }
    __syncthreads();

    // A-frags to registers: own 64 rows (tiles wr*4 .. wr*4+3), full K.
    half8 A[4][8];
#pragma unroll
    for (int rt = 0; rt < 4; ++rt)
#pragma unroll
        for (int kf = 0; kf < 8; ++kf)
            A[rt][kf] = *(const half8*)(smem + (((wr * 4 + rt) * 8 + kf) * 64 + l) * 8);
    __syncthreads();   // smem dead until final reduce

    // B stream base: this wave's col group, this lane's frag slot.
    // byte offset of (tile t, kf) = t*32768 + wc*8192 + kf*1024 + l*16.
    const _Float16* bb = ph + wc * 4096 + (size_t)l * 8;   // half units

    half8 Bf[4];
    Bf[0] = *(const half8*)(bb + 0);
    Bf[1] = *(const half8*)(bb + 512);
    Bf[2] = *(const half8*)(bb + 1024);
    Bf[3] = *(const half8*)(bb + 1536);

    float t1[16], t2[16];
    int ic[16];
#pragma unroll
    for (int s = 0; s < 16; ++s) { t1[s] = -FLT_MAX; t2[s] = -FLT_MAX; ic[s] = 0; }

    for (int t = 0; t < 32; ++t) {
        const _Float16* bt = bb + t * 16384;
        f32x4 a0 = {}, a1 = {}, a2 = {}, a3 = {};
#pragma unroll
        for (int k = 0; k < 8; ++k) {
            half8 B = Bf[k & 3];
            // reissue for step k+4 (tail t=31,k>=4 overruns into pl: mapped, unused)
            Bf[k & 3] = *(const half8*)(bt + ((k < 4) ? (k + 4) * 512
                                                      : (16384 + (k - 4) * 512)));
            a0 = __builtin_amdgcn_mfma_f32_16x16x32_f16(A[0][k], B, a0, 0, 0, 0);
            a1 = __builtin_amdgcn_mfma_f32_16x16x32_f16(A[1][k], B, a1, 0, 0, 0);
            a2 = __builtin_amdgcn_mfma_f32_16x16x32_f16(A[2][k], B, a2, 0, 0, 0);
            a3 = __builtin_amdgcn_mfma_f32_16x16x32_f16(A[3][k], B, a3, 0, 0, 0);
        }
#define UPD(ACC, RT)                                                       \
        _Pragma("unroll")                                                  \
        for (int reg = 0; reg < 4; ++reg) {                                \
            int s = (RT) * 4 + reg;                                        \
            float v = (ACC)[reg];                                          \
            float nt2 = __builtin_amdgcn_fmed3f(t1[s], t2[s], v);          \
            ic[s] = (v > t1[s]) ? t : ic[s];                               \
            t1[s] = fmaxf(t1[s], v);                                       \
            t2[s] = nt2;                                                   \
        }
        UPD(a0, 0) UPD(a1, 1) UPD(a2, 2) UPD(a3, 3)
#undef UPD
    }

    // Butterfly across the 16 column lanes (masks < 16 keep l>>4 fixed).
    int idx[16];
#pragma unroll
    for (int s = 0; s < 16; ++s) idx[s] = (ic[s] * 4 + wc) * 16 + (l & 15);
#pragma unroll
    for (int m = 1; m <= 8; m <<= 1) {
#pragma unroll
        for (int s = 0; s < 16; ++s) {
            float ot1 = __shfl_xor(t1[s], m, 64);
            int   oi  = __shfl_xor(idx[s], m, 64);
            float ot2 = __shfl_xor(t2[s], m, 64);
            float nt2 = fmaxf(fminf(t1[s], ot1), fmaxf(t2[s], ot2));
            if (ot1 > t1[s] || (ot1 == t1[s] && oi < idx[s])) { t1[s] = ot1; idx[s] = oi; }
            t2[s] = nt2;
        }
    }

    // Per-wave partials -> LDS; combine across col groups.
    float* rT1 = (float*)smem;          // 512
    int*   rI1 = (int*)smem + 512;
    float* rT2 = (float*)smem + 1024;
    if ((l & 15) == 0) {
#pragma unroll
        for (int rt = 0; rt < 4; ++rt)
#pragma unroll
            for (int reg = 0; reg < 4; ++reg) {
                int s = rt * 4 + reg;
                int row = wr * 64 + rt * 16 + (l >> 4) * 4 + reg;
                rT1[row * 4 + wc] = t1[s];
                rI1[row * 4 + wc] = idx[s];
                rT2[row * 4 + wc] = t2[s];
            }
    }
    __syncthreads();
    if (tid < 128) {
        float T1 = -FLT_MAX, T2 = -FLT_MAX; int I1 = 0x7FFFFFFF;
#pragma unroll
        for (int g = 0; g < 4; ++g) {
            float v1 = rT1[tid * 4 + g];
            int   vi = rI1[tid * 4 + g];
            float v2 = rT2[tid * 4 + g];
            float nt2 = fmaxf(fminf(T1, v1), fmaxf(T2, v2));
            if (v1 > T1 || (v1 == T1 && vi < I1)) { T1 = v1; I1 = vi; }
            T2 = nt2;
        }
        int grow = blockIdx.x * 128 + tid;
        out[grow] = I1;
        if (T1 - T2 < M1) {
            int pos = atomicAdd(c1, 1);
            if (pos < CAP1) l1[pos] = grow;
        }
    }
}

// ---------------------------------------------------------------------------
// Kernel B: fp16x2 3-pass MFMA on flagged rows, barrier-free K-loop.
// Block = 16 rows, 256 thr = 4 waves (wc = col group). A hi/lo in 64 VGPRs;
// B hi/lo streamed global->VGPR with depth-4 rotation. Same accumulation
// order as round-3 (bit-identical sims).
// ---------------------------------------------------------------------------
__launch_bounds__(256, 2)
__global__ void pc_rescue2(const float* __restrict__ x, const _Float16* __restrict__ ph,
                           const _Float16* __restrict__ pl,
                           const int* __restrict__ c1, const int* __restrict__ l1,
                           int* __restrict__ out, int* __restrict__ c2,
                           int* __restrict__ l2) {
    const int n0 = *c1;
    const int n = n0 < CAP1 ? n0 : CAP1;
    const int base = blockIdx.x * 16;
    if (base >= n) return;
    const int tid = threadIdx.x;
    const int l = tid & 63, wc = tid >> 6;

    const int rslot = base + (l & 15);
    const int my_row = l1[rslot < n ? rslot : (n - 1)];

    half8 Ah[8], Al[8];
#pragma unroll
    for (int kf = 0; kf < 8; ++kf) {
        const float* s = x + (size_t)my_row * 256 + kf * 32 + (l >> 4) * 8;
        float4 a = *(const float4*)s, b = *(const float4*)(s + 4);
        float v[8] = {a.x, a.y, a.z, a.w, b.x, b.y, b.z, b.w};
#pragma unroll
        for (int j = 0; j < 8; ++j) {
            _Float16 hi = (_Float16)v[j];
            Ah[kf][j] = hi;
            Al[kf][j] = (_Float16)((v[j] - (float)hi) * 2048.0f);
        }
    }

    const _Float16* bh = ph + wc * 4096 + (size_t)l * 8;
    const _Float16* bl = pl + wc * 4096 + (size_t)l * 8;
    half8 BH[4], BL[4];
#pragma unroll
    for (int j = 0; j < 4; ++j) {
        BH[j] = *(const half8*)(bh + j * 512);
        BL[j] = *(const half8*)(bl + j * 512);
    }

    float t1[4], t2[4];
    int ic[4];
#pragma unroll
    for (int s = 0; s < 4; ++s) { t1[s] = -FLT_MAX; t2[s] = -FLT_MAX; ic[s] = 0; }

    for (int t = 0; t < 32; ++t) {
        const _Float16* bth = bh + t * 16384;
        const _Float16* btl = bl + t * 16384;
        f32x4 hh = {}, hl = {}, lh = {};
#pragma unroll
        for (int k = 0; k < 8; ++k) {
            half8 Bh_ = BH[k & 3], Bl_ = BL[k & 3];
            int off = (k < 4) ? (k + 4) * 512 : (16384 + (k - 4) * 512);
            BH[k & 3] = *(const half8*)(bth + off);
            BL[k & 3] = *(const half8*)(btl + off);
            hh = __builtin_amdgcn_mfma_f32_16x16x32_f16(Ah[k], Bh_, hh, 0, 0, 0);
            hl = __builtin_amdgcn_mfma_f32_16x16x32_f16(Ah[k], Bl_, hl, 0, 0, 0);
            lh = __builtin_amdgcn_mfma_f32_16x16x32_f16(Al[k], Bh_, lh, 0, 0, 0);
        }
#pragma unroll
        for (int reg = 0; reg < 4; ++reg) {
            float v = hh[reg] + (hl[reg] + lh[reg]) * (1.0f / 2048.0f);
            float nt2 = __builtin_amdgcn_fmed3f(t1[reg], t2[reg], v);
            ic[reg] = (v > t1[reg]) ? t : ic[reg];
            t1[reg] = fmaxf(t1[reg], v);
            t2[reg] = nt2;
        }
    }

    int idx[4];
#pragma unroll
    for (int s = 0; s < 4; ++s) idx[s] = (ic[s] * 4 + wc) * 16 + (l & 15);
#pragma unroll
    for (int m = 1; m <= 8; m <<= 1) {
#pragma unroll
        for (int s = 0; s < 4; ++s) {
            float ot1 = __shfl_xor(t1[s], m, 64);
            int   oi  = __shfl_xor(idx[s], m, 64);
            float ot2 = __shfl_xor(t2[s], m, 64);
            float nt2 = fmaxf(fminf(t1[s], ot1), fmaxf(t2[s], ot2));
            if (ot1 > t1[s] || (ot1 == t1[s] && oi < idx[s])) { t1[s] = ot1; idx[s] = oi; }
            t2[s] = nt2;
        }
    }

    __shared__ float rT1[64];
    __shared__ int   rI1[64];
    __shared__ float rT2[64];
    if ((l & 15) == 0) {
#pragma unroll
        for (int reg = 0; reg < 4; ++reg) {
            int r = (l >> 4) * 4 + reg;
            rT1[r * 4 + wc] = t1[reg];
            rI1[r * 4 + wc] = idx[reg];
            rT2[r * 4 + wc] = t2[reg];
        }
    }
    __syncthreads();
    if (tid < 16) {
        float T1 = -FLT_MAX, T2 = -FLT_MAX; int I1 = 0x7FFFFFFF;
#pragma unroll
        for (int g = 0; g < 4; ++g) {
            float v1 = rT1[tid * 4 + g];
            int   vi = rI1[tid * 4 + g];
            float v2 = rT2[tid * 4 + g];
            float nt2 = fmaxf(fminf(T1, v1), fmaxf(T2, v2));
            if (v1 > T1 || (v1 == T1 && vi < I1)) { T1 = v1; I1 = vi; }
            T2 = nt2;
        }
        int slot = base + tid;
        if (slot < n) {
            int grow = l1[slot];
            out[grow] = I1;
            if (T1 - T2 < M2) {
                int pos = atomicAdd(c2, 1);
                if (pos < CAP2) l2[pos] = grow;
            }
        }
    }
}

// ---------------------------------------------------------------------------
// Kernel C: exact fp32 argmax for residual rows (expected ~25).
// UNCHANGED arithmetic from round 3 (verified to match numpy on this dataset).
// ---------------------------------------------------------------------------
__global__ void rescue3(const float* __restrict__ x, const float* __restrict__ p,
                        const int* __restrict__ count, const int* __restrict__ list,
                        int* __restrict__ out) {
    __shared__ float xrow[256];
    __shared__ float pch[32][260];
    __shared__ float red2[32][9];
    __shared__ float bvs[32];
    __shared__ int   bis[32];
    const int tid = threadIdx.x;
    const int n0 = *count;
    const int n = n0 < CAP2 ? n0 : CAP2;
    for (int e = blockIdx.x; e < n; e += gridDim.x) {
        const int row = list[e];
        __syncthreads();
        if (tid < 64) {
            float4 v = *(const float4*)(x + (size_t)row * 256 + tid * 4);
            *(float4*)(&xrow[tid * 4]) = v;
        }
        float bv = -FLT_MAX; int bi = 0;
        const int cell = tid & 31, kq = tid >> 5;
        for (int c0 = 0; c0 < NUM_CELLS; c0 += 32) {
            __syncthreads();
#pragma unroll
            for (int i = 0; i < 8; ++i) {
                int f = tid + i * 256;
                int cr = f >> 6, k4 = (f & 63) * 4;
                float4 v = *(const float4*)(p + (size_t)(c0 + cr) * 256 + k4);
                *(float4*)(&pch[cr][k4]) = v;
            }
            __syncthreads();
            float s = 0.f;
#pragma unroll
            for (int j = 0; j < 8; ++j) {
                float4 pv = *(const float4*)(&pch[cell][kq * 32 + j * 4]);
                float4 xv = *(const float4*)(&xrow[kq * 32 + j * 4]);
                s = fmaf(xv.x, pv.x, s); s = fmaf(xv.y, pv.y, s);
                s = fmaf(xv.z, pv.z, s); s = fmaf(xv.w, pv.w, s);
            }
            red2[cell][kq] = s;
            __syncthreads();
            if (tid < 32) {
                float dot = 0.f;
#pragma unroll
                for (int q = 0; q < 8; ++q) dot += red2[tid][q];
                if (dot > bv) { bv = dot; bi = c0 + tid; }
            }
        }
        if (tid < 32) { bvs[tid] = bv; bis[tid] = bi; }
        __syncthreads();
        if (tid == 0) {
            float B = bvs[0]; int BI = bis[0];
#pragma unroll
            for (int t = 1; t < 32; ++t)
                if (bvs[t] > B || (bvs[t] == B && bis[t] < BI)) { B = bvs[t]; BI = bis[t]; }
            out[row] = BI;
        }
    }
}

// ---------------------------------------------------------------------------
// Fallback (round-1 fp32 vector path) if ws too small.
// ---------------------------------------------------------------------------
#define BM 64
#define BN 64
#define BK 32
#define XP 260
#define PP 68
__launch_bounds__(256, 2)
__global__ void placecells_argmax_fp32(const float* __restrict__ x,
                                       const float* __restrict__ pc,
                                       int* __restrict__ out) {
    __shared__ float xs[BM * XP];
    __shared__ float ps[BK * PP];
    const int tid = threadIdx.x;
    const int tx = tid & 15;
    const int ty = tid >> 4;
    const float* xg = x + (size_t)blockIdx.x * (BM * CELL_DIM);
#pragma unroll
    for (int i = 0; i < 16; ++i) {
        int f = tid + i * 256;
        int s = f >> 6, k4 = (f & 63) << 2;
        *(float4*)(&xs[s * XP + k4]) = *(const float4*)(xg + s * CELL_DIM + k4);
    }
    __syncthreads();
    float runv[4]; int runi[4];
#pragma unroll
    for (int si = 0; si < 4; ++si) { runv[si] = -FLT_MAX; runi[si] = 0; }
    for (int jc = 0; jc < NUM_CELLS; jc += BN) {
        float acc[4][4];
#pragma unroll
        for (int si = 0; si < 4; ++si)
#pragma unroll
            for (int cj = 0; cj < 4; ++cj) acc[si][cj] = 0.0f;
        for (int kc = 0; kc < CELL_DIM; kc += BK) {
            __syncthreads();
#pragma unroll
            for (int i = 0; i < 2; ++i) {
                int f = tid + i * 256;
                int c = f >> 3, k4 = (f & 7) << 2;
                float4 v = *(const float4*)(pc + (size_t)(jc + c) * CELL_DIM + kc + k4);
                ps[(k4 + 0) * PP + c] = v.x; ps[(k4 + 1) * PP + c] = v.y;
                ps[(k4 + 2) * PP + c] = v.z; ps[(k4 + 3) * PP + c] = v.w;
            }
            __syncthreads();
#pragma unroll
            for (int kk = 0; kk < BK; kk += 4) {
                float4 xv[4];
#pragma unroll
                for (int si = 0; si < 4; ++si)
                    xv[si] = *(const float4*)(&xs[(ty * 4 + si) * XP + kc + kk]);
#pragma unroll
                for (int kt = 0; kt < 4; ++kt) {
                    float4 pv = *(const float4*)(&ps[(kk + kt) * PP + tx * 4]);
#pragma unroll
                    for (int si = 0; si < 4; ++si) {
                        float xk = (kt == 0) ? xv[si].x : (kt == 1) ? xv[si].y :
                                   (kt == 2) ? xv[si].z : xv[si].w;
                        acc[si][0] = fmaf(xk, pv.x, acc[si][0]);
                        acc[si][1] = fmaf(xk, pv.y, acc[si][1]);
                        acc[si][2] = fmaf(xk, pv.z, acc[si][2]);
                        acc[si][3] = fmaf(xk, pv.w, acc[si][3]);
                    }
                }
            }
        }
#pragma unroll
        for (int si = 0; si < 4; ++si)
#pragma unroll
            for (int cj = 0; cj < 4; ++cj) {
                int idx = jc + tx * 4 + cj;
                if (acc[si][cj] > runv[si]) { runv[si] = acc[si][cj]; runi[si] = idx; }
            }
    }
    __syncthreads();
    float* rv = ps; int* ri = (int*)(ps + 1024);
#pragma unroll
    for (int si = 0; si < 4; ++si) {
        int s = ty * 4 + si;
        rv[s * 16 + tx] = runv[si]; ri[s * 16 + tx] = runi[si];
    }
    __syncthreads();
    if (tid < BM) {
        float bv = rv[tid * 16]; int bi = ri[tid * 16];
#pragma unroll
        for (int t = 1; t < 16; ++t) {
            float v = rv[tid * 16 + t]; int i = ri[tid * 16 + t];
            if (v > bv || (v == bv && i < bi)) { bv = v; bi = i; }
        }
        out[(size_t)blockIdx.x * BM + tid] = bi;
    }
}

extern "C" void kernel_launch(void* const* d_in, const int* in_sizes, int n_in,
                              void* d_out, int out_size, void* d_ws, size_t ws_size,
                              hipStream_t stream) {
    const float* x  = (const float*)d_in[0];   // (131072, 256) fp32
    const float* pc = (const float*)d_in[1];   // (2048, 256) fp32
    int* out = (int*)d_out;

    if (ws_size >= (size_t)WS_NEEDED) {
        char* ws = (char*)d_ws;
        int* c1 = (int*)(ws + WS_C1);
        int* c2 = (int*)(ws + WS_C2);
        int* l1 = (int*)(ws + WS_L1);
        int* l2 = (int*)(ws + WS_L2);
        _Float16* ph = (_Float16*)(ws + WS_PH);
        _Float16* pl = (_Float16*)(ws + WS_PL);
        prep_p<<<256, 256, 0, stream>>>(pc, ph, pl, c1, c2);
        pc_gemm1<<<N_STATES / 128, 512, 0, stream>>>(x, ph, out, c1, l1);
        pc_rescue2<<<CAP1 / 16, 256, 0, stream>>>(x, ph, pl, c1, l1, out, c2, l2);
        rescue3<<<128, 256, 0, stream>>>(x, pc, c2, l2, out);
    } else {
        placecells_argmax_fp32<<<N_STATES / BM, 256, 0, stream>>>(x, pc, out);
    }
}

// Round 5
// 501.259 us; speedup vs baseline: 1.0269x; 1.0269x over previous
//
#include <hip/hip_runtime.h>
#include <float.h>
#include <stdint.h>

#define NUM_CELLS 2048
#define CELL_DIM  256
#define N_STATES  131072

typedef _Float16 half8 __attribute__((ext_vector_type(8)));
typedef float    f32x4 __attribute__((ext_vector_type(4)));
typedef float    f32x4v __attribute__((ext_vector_type(4)));   // nt-load-able

// Stage-1 (1-pass fp16) sim-difference noise sigma ~6e-3; M1 ~ 17 sigma.
#define M1 0.10f
// Stage-2 (fp16x2 3-pass) noise sigma ~1.5e-5; M2 = 0.0008 ~ 50 sigma.
#define M2 0.0008f
#define CAP1 32768
#define CAP2 4096

// ws layout (bytes). ws_size >= WS_NEEDED confirmed (rounds 2-4 ran this path).
#define WS_C1 0
#define WS_C2 4
#define WS_L1 1024
#define WS_L2 (WS_L1 + 4 * CAP1)                    // 132096
#define WS_PH 262144
#define WS_PL (WS_PH + 1048576)
// 128 KB slack after pl: B-stream rotation tail prefetch overruns (loads are
// issued but never consumed) — must be mapped.
#define WS_NEEDED (WS_PL + 1048576 + 131072)        // 2490368

// ---------------------------------------------------------------------------
// Prep: p fp32 -> B-fragment-order fp16 hi + (lo*2048) arrays; zero counters.
// Frag order (16x16x32 f16 B): half8 index d = (ct*8 + kf)*64 + l, where
// cell = ct*16 + (l&15), k = kf*32 + (l>>4)*8 + j.
// ---------------------------------------------------------------------------
__global__ void prep_p(const float* __restrict__ p, _Float16* __restrict__ ph,
                       _Float16* __restrict__ pl, int* __restrict__ c1,
                       int* __restrict__ c2) {
    int d = blockIdx.x * 256 + threadIdx.x;   // 65536 dests
    if (d == 0) { *c1 = 0; *c2 = 0; }
    int l = d & 63, kf = (d >> 6) & 7, ct = d >> 9;
    int cell = ct * 16 + (l & 15);
    int k0 = kf * 32 + (l >> 4) * 8;
    const float* s = p + cell * 256 + k0;
    float4 a = *(const float4*)s, b = *(const float4*)(s + 4);
    float v[8] = {a.x, a.y, a.z, a.w, b.x, b.y, b.z, b.w};
    half8 h, lo;
#pragma unroll
    for (int j = 0; j < 8; ++j) {
        _Float16 hi = (_Float16)v[j];
        h[j] = hi;
        lo[j] = (_Float16)((v[j] - (float)hi) * 2048.0f);  // scaled: no fp16 denorms
    }
    *(half8*)(ph + (size_t)d * 8) = h;
    *(half8*)(pl + (size_t)d * 8) = lo;
}

// ---------------------------------------------------------------------------
// Kernel A: 1-pass fp16 MFMA GEMM, barrier-free K-loop.
// Block = 128 rows; 512 thr = 8 waves (wr 0..1 row half x wc 0..3 col group).
// A-frags (64 rows x K=256) in 128 VGPRs. B streamed global->VGPR from
// frag-order ph with DEPTH-8 rotation (covers ~310 cyc at 2 waves/SIMD).
// x loaded NON-TEMPORALLY so the 84 MB x stream does not evict ph from L2.
// ---------------------------------------------------------------------------
__launch_bounds__(512, 2)
__global__ void pc_gemm1(const float* __restrict__ x, const _Float16* __restrict__ ph,
                         int* __restrict__ out, int* __restrict__ c1,
                         int* __restrict__ l1) {
    __shared__ _Float16 smem[32768];   // 64 KB: x-frag staging, then reduce buf

    const int tid = threadIdx.x;
    const int l = tid & 63;
    const int w = tid >> 6;
    const int wr = w >> 2, wc = w & 3;

    // Phase 1: x fp32 -> fp16 A-frag order in LDS (once per block). NT loads.
    const float* xg = x + (size_t)blockIdx.x * (128 * CELL_DIM);
#pragma unroll
    for (int i = 0; i < 8; ++i) {
        int d = tid + i * 512;            // 4096 half8 dests
        int dl = d & 63, kf = (d >> 6) & 7, rt = d >> 9;
        int row = rt * 16 + (dl & 15);
        int k0 = kf * 32 + (dl >> 4) * 8;
        const f32x4v* s = (const f32x4v*)(xg + row * 256 + k0);
        f32x4v a = __builtin_nontemporal_load(s);
        f32x4v b = __builtin_nontemporal_load(s + 1);
        half8 h;
        h[0] = (_Float16)a[0]; h[1] = (_Float16)a[1];
        h[2] = (_Float16)a[2]; h[3] = (_Float16)a[3];
        h[4] = (_Float16)b[0]; h[5] = (_Float16)b[1];
        h[6] = (_Float16)b[2]; h[7] = (_Float16)b[3];
        *(half8*)(smem + d * 8) = h;
    }
    __syncthreads();

    // A-frags to registers: own 64 rows (tiles wr*4 .. wr*4+3), full K.
    half8 A[4][8];
#pragma unroll
    for (int rt = 0; rt < 4; ++rt)
#pragma unroll
        for (int kf = 0; kf < 8; ++kf)
            A[rt][kf] = *(const half8*)(smem + (((wr * 4 + rt) * 8 + kf) * 64 + l) * 8);
    __syncthreads();   // smem dead until final reduce

    // B stream: per tile t, wave wc handles cell-tile ct = t*4 + wc (16 cells).
    // byte offset of (t, kf) = t*32768 + wc*8192 + kf*1024 + l*16.
    const _Float16* bb = ph + wc * 4096 + (size_t)l * 8;   // half units

    half8 Bf[8];
#pragma unroll
    for (int j = 0; j < 8; ++j) Bf[j] = *(const half8*)(bb + j * 512);

    float t1[16], t2[16];
    int ic[16];
#pragma unroll
    for (int s = 0; s < 16; ++s) { t1[s] = -FLT_MAX; t2[s] = -FLT_MAX; ic[s] = 0; }

    for (int t = 0; t < 32; ++t) {
        const _Float16* bn = bb + (t + 1) * 16384;   // next tile's frags
        f32x4 a0 = {}, a1 = {}, a2 = {}, a3 = {};
#pragma unroll
        for (int k = 0; k < 8; ++k) {
            half8 B = Bf[k];
            // reissue for tile t+1, same kf (8 outstanding; tail overruns into pl)
            Bf[k] = *(const half8*)(bn + k * 512);
            a0 = __builtin_amdgcn_mfma_f32_16x16x32_f16(A[0][k], B, a0, 0, 0, 0);
            a1 = __builtin_amdgcn_mfma_f32_16x16x32_f16(A[1][k], B, a1, 0, 0, 0);
            a2 = __builtin_amdgcn_mfma_f32_16x16x32_f16(A[2][k], B, a2, 0, 0, 0);
            a3 = __builtin_amdgcn_mfma_f32_16x16x32_f16(A[3][k], B, a3, 0, 0, 0);
        }
#define UPD(ACC, RT)                                                       \
        _Pragma("unroll")                                                  \
        for (int reg = 0; reg < 4; ++reg) {                                \
            int s = (RT) * 4 + reg;                                        \
            float v = (ACC)[reg];                                          \
            float nt2 = __builtin_amdgcn_fmed3f(t1[s], t2[s], v);          \
            ic[s] = (v > t1[s]) ? t : ic[s];                               \
            t1[s] = fmaxf(t1[s], v);                                       \
            t2[s] = nt2;                                                   \
        }
        UPD(a0, 0) UPD(a1, 1) UPD(a2, 2) UPD(a3, 3)
#undef UPD
    }

    // Butterfly across the 16 column lanes (masks < 16 keep l>>4 fixed).
    int idx[16];
#pragma unroll
    for (int s = 0; s < 16; ++s) idx[s] = (ic[s] * 4 + wc) * 16 + (l & 15);
#pragma unroll
    for (int m = 1; m <= 8; m <<= 1) {
#pragma unroll
        for (int s = 0; s < 16; ++s) {
            float ot1 = __shfl_xor(t1[s], m, 64);
            int   oi  = __shfl_xor(idx[s], m, 64);
            float ot2 = __shfl_xor(t2[s], m, 64);
            float nt2 = fmaxf(fminf(t1[s], ot1), fmaxf(t2[s], ot2));
            if (ot1 > t1[s] || (ot1 == t1[s] && oi < idx[s])) { t1[s] = ot1; idx[s] = oi; }
            t2[s] = nt2;
        }
    }

    // Per-wave partials -> LDS; combine across col groups.
    float* rT1 = (float*)smem;          // 512
    int*   rI1 = (int*)smem + 512;
    float* rT2 = (float*)smem + 1024;
    if ((l & 15) == 0) {
#pragma unroll
        for (int rt = 0; rt < 4; ++rt)
#pragma unroll
            for (int reg = 0; reg < 4; ++reg) {
                int s = rt * 4 + reg;
                int row = wr * 64 + rt * 16 + (l >> 4) * 4 + reg;
                rT1[row * 4 + wc] = t1[s];
                rI1[row * 4 + wc] = idx[s];
                rT2[row * 4 + wc] = t2[s];
            }
    }
    __syncthreads();
    if (tid < 128) {
        float T1 = -FLT_MAX, T2 = -FLT_MAX; int I1 = 0x7FFFFFFF;
#pragma unroll
        for (int g = 0; g < 4; ++g) {
            float v1 = rT1[tid * 4 + g];
            int   vi = rI1[tid * 4 + g];
            float v2 = rT2[tid * 4 + g];
            float nt2 = fmaxf(fminf(T1, v1), fmaxf(T2, v2));
            if (v1 > T1 || (v1 == T1 && vi < I1)) { T1 = v1; I1 = vi; }
            T2 = nt2;
        }
        int grow = blockIdx.x * 128 + tid;
        out[grow] = I1;
        // Ballot-compacted flag write: 1 atomic per wave (2 per block), not
        // one per flagged row (r3/r4 had ~4000 same-address atomics chip-wide).
        bool f = (T1 - T2 < M1);
        unsigned long long msk = __ballot(f);
        int cnt = __popcll(msk);
        int prefix = __popcll(msk & ((1ull << l) - 1ull));
        int bpos = 0;
        if (l == 0 && cnt) bpos = atomicAdd(c1, cnt);
        bpos = __shfl(bpos, 0, 64);
        if (f) {
            int pos = bpos + prefix;
            if (pos < CAP1) l1[pos] = grow;
        }
    }
}

// ---------------------------------------------------------------------------
// Kernel B: fp16x2 3-pass MFMA on flagged rows, barrier-free K-loop.
// Grid-stride over 16-row groups (grid 256). 256 thr = 4 waves (wc = col
// group). Per-sim arithmetic IDENTICAL to rounds 3-4 (verified absmax 0).
// ---------------------------------------------------------------------------
__launch_bounds__(256, 2)
__global__ void pc_rescue2(const float* __restrict__ x, const _Float16* __restrict__ ph,
                           const _Float16* __restrict__ pl,
                           const int* __restrict__ c1, const int* __restrict__ l1,
                           int* __restrict__ out, int* __restrict__ c2,
                           int* __restrict__ l2) {
    const int n0 = *c1;
    const int n = n0 < CAP1 ? n0 : CAP1;
    const int G = (n + 15) >> 4;
    const int tid = threadIdx.x;
    const int l = tid & 63, wc = tid >> 6;

    __shared__ float rT1[64];
    __shared__ int   rI1[64];
    __shared__ float rT2[64];

    for (int g = blockIdx.x; g < G; g += gridDim.x) {
        const int base = g * 16;
        __syncthreads();   // protect shared reuse across group iterations

        const int rslot = base + (l & 15);
        const int my_row = l1[rslot < n ? rslot : (n - 1)];

        half8 Ah[8], Al[8];
#pragma unroll
        for (int kf = 0; kf < 8; ++kf) {
            const float* s = x + (size_t)my_row * 256 + kf * 32 + (l >> 4) * 8;
            float4 a = *(const float4*)s, b = *(const float4*)(s + 4);
            float v[8] = {a.x, a.y, a.z, a.w, b.x, b.y, b.z, b.w};
#pragma unroll
            for (int j = 0; j < 8; ++j) {
                _Float16 hi = (_Float16)v[j];
                Ah[kf][j] = hi;
                Al[kf][j] = (_Float16)((v[j] - (float)hi) * 2048.0f);
            }
        }

        const _Float16* bh = ph + wc * 4096 + (size_t)l * 8;
        const _Float16* bl = pl + wc * 4096 + (size_t)l * 8;
        half8 BH[4], BL[4];
#pragma unroll
        for (int j = 0; j < 4; ++j) {
            BH[j] = *(const half8*)(bh + j * 512);
            BL[j] = *(const half8*)(bl + j * 512);
        }

        float t1[4], t2[4];
        int ic[4];
#pragma unroll
        for (int s = 0; s < 4; ++s) { t1[s] = -FLT_MAX; t2[s] = -FLT_MAX; ic[s] = 0; }

        for (int t = 0; t < 32; ++t) {
            const _Float16* bth = bh + t * 16384;
            const _Float16* btl = bl + t * 16384;
            f32x4 hh = {}, hl = {}, lh = {};
#pragma unroll
            for (int k = 0; k < 8; ++k) {
                half8 Bh_ = BH[k & 3], Bl_ = BL[k & 3];
                int off = (k < 4) ? (k + 4) * 512 : (16384 + (k - 4) * 512);
                BH[k & 3] = *(const half8*)(bth + off);
                BL[k & 3] = *(const half8*)(btl + off);
                hh = __builtin_amdgcn_mfma_f32_16x16x32_f16(Ah[k], Bh_, hh, 0, 0, 0);
                hl = __builtin_amdgcn_mfma_f32_16x16x32_f16(Ah[k], Bl_, hl, 0, 0, 0);
                lh = __builtin_amdgcn_mfma_f32_16x16x32_f16(Al[k], Bh_, lh, 0, 0, 0);
            }
#pragma unroll
            for (int reg = 0; reg < 4; ++reg) {
                float v = hh[reg] + (hl[reg] + lh[reg]) * (1.0f / 2048.0f);
                float nt2 = __builtin_amdgcn_fmed3f(t1[reg], t2[reg], v);
                ic[reg] = (v > t1[reg]) ? t : ic[reg];
                t1[reg] = fmaxf(t1[reg], v);
                t2[reg] = nt2;
            }
        }

        int idx[4];
#pragma unroll
        for (int s = 0; s < 4; ++s) idx[s] = (ic[s] * 4 + wc) * 16 + (l & 15);
#pragma unroll
        for (int m = 1; m <= 8; m <<= 1) {
#pragma unroll
            for (int s = 0; s < 4; ++s) {
                float ot1 = __shfl_xor(t1[s], m, 64);
                int   oi  = __shfl_xor(idx[s], m, 64);
                float ot2 = __shfl_xor(t2[s], m, 64);
                float nt2 = fmaxf(fminf(t1[s], ot1), fmaxf(t2[s], ot2));
                if (ot1 > t1[s] || (ot1 == t1[s] && oi < idx[s])) { t1[s] = ot1; idx[s] = oi; }
                t2[s] = nt2;
            }
        }

        if ((l & 15) == 0) {
#pragma unroll
            for (int reg = 0; reg < 4; ++reg) {
                int r = (l >> 4) * 4 + reg;
                rT1[r * 4 + wc] = t1[reg];
                rI1[r * 4 + wc] = idx[reg];
                rT2[r * 4 + wc] = t2[reg];
            }
        }
        __syncthreads();
        if (tid < 16) {
            float T1 = -FLT_MAX, T2 = -FLT_MAX; int I1 = 0x7FFFFFFF;
#pragma unroll
            for (int q = 0; q < 4; ++q) {
                float v1 = rT1[tid * 4 + q];
                int   vi = rI1[tid * 4 + q];
                float v2 = rT2[tid * 4 + q];
                float nt2 = fmaxf(fminf(T1, v1), fmaxf(T2, v2));
                if (v1 > T1 || (v1 == T1 && vi < I1)) { T1 = v1; I1 = vi; }
                T2 = nt2;
            }
            int slot = base + tid;
            if (slot < n) {
                int grow = l1[slot];
                out[grow] = I1;
                if (T1 - T2 < M2) {
                    int pos = atomicAdd(c2, 1);
                    if (pos < CAP2) l2[pos] = grow;
                }
            }
        }
    }
}

// ---------------------------------------------------------------------------
// Kernel C: exact fp32 argmax for residual rows (expected ~30).
// UNCHANGED arithmetic from rounds 2-4 (matches numpy on this dataset).
// ---------------------------------------------------------------------------
__global__ void rescue3(const float* __restrict__ x, const float* __restrict__ p,
                        const int* __restrict__ count, const int* __restrict__ list,
                        int* __restrict__ out) {
    __shared__ float xrow[256];
    __shared__ float pch[32][260];
    __shared__ float red2[32][9];
    __shared__ float bvs[32];
    __shared__ int   bis[32];
    const int tid = threadIdx.x;
    const int n0 = *count;
    const int n = n0 < CAP2 ? n0 : CAP2;
    for (int e = blockIdx.x; e < n; e += gridDim.x) {
        const int row = list[e];
        __syncthreads();
        if (tid < 64) {
            float4 v = *(const float4*)(x + (size_t)row * 256 + tid * 4);
            *(float4*)(&xrow[tid * 4]) = v;
        }
        float bv = -FLT_MAX; int bi = 0;
        const int cell = tid & 31, kq = tid >> 5;
        for (int c0 = 0; c0 < NUM_CELLS; c0 += 32) {
            __syncthreads();
#pragma unroll
            for (int i = 0; i < 8; ++i) {
                int f = tid + i * 256;
                int cr = f >> 6, k4 = (f & 63) * 4;
                float4 v = *(const float4*)(p + (size_t)(c0 + cr) * 256 + k4);
                *(float4*)(&pch[cr][k4]) = v;
            }
            __syncthreads();
            float s = 0.f;
#pragma unroll
            for (int j = 0; j < 8; ++j) {
                float4 pv = *(const float4*)(&pch[cell][kq * 32 + j * 4]);
                float4 xv = *(const float4*)(&xrow[kq * 32 + j * 4]);
                s = fmaf(xv.x, pv.x, s); s = fmaf(xv.y, pv.y, s);
                s = fmaf(xv.z, pv.z, s); s = fmaf(xv.w, pv.w, s);
            }
            red2[cell][kq] = s;
            __syncthreads();
            if (tid < 32) {
                float dot = 0.f;
#pragma unroll
                for (int q = 0; q < 8; ++q) dot += red2[tid][q];
                if (dot > bv) { bv = dot; bi = c0 + tid; }
            }
        }
        if (tid < 32) { bvs[tid] = bv; bis[tid] = bi; }
        __syncthreads();
        if (tid == 0) {
            float B = bvs[0]; int BI = bis[0];
#pragma unroll
            for (int t = 1; t < 32; ++t)
                if (bvs[t] > B || (bvs[t] == B && bis[t] < BI)) { B = bvs[t]; BI = bis[t]; }
            out[row] = BI;
        }
    }
}

// ---------------------------------------------------------------------------
// Fallback (round-1 fp32 vector path) if ws too small.
// ---------------------------------------------------------------------------
#define BM 64
#define BN 64
#define BK 32
#define XP 260
#define PP 68
__launch_bounds__(256, 2)
__global__ void placecells_argmax_fp32(const float* __restrict__ x,
                                       const float* __restrict__ pc,
                                       int* __restrict__ out) {
    __shared__ float xs[BM * XP];
    __shared__ float ps[BK * PP];
    const int tid = threadIdx.x;
    const int tx = tid & 15;
    const int ty = tid >> 4;
    const float* xg = x + (size_t)blockIdx.x * (BM * CELL_DIM);
#pragma unroll
    for (int i = 0; i < 16; ++i) {
        int f = tid + i * 256;
        int s = f >> 6, k4 = (f & 63) << 2;
        *(float4*)(&xs[s * XP + k4]) = *(const float4*)(xg + s * CELL_DIM + k4);
    }
    __syncthreads();
    float runv[4]; int runi[4];
#pragma unroll
    for (int si = 0; si < 4; ++si) { runv[si] = -FLT_MAX; runi[si] = 0; }
    for (int jc = 0; jc < NUM_CELLS; jc += BN) {
        float acc[4][4];
#pragma unroll
        for (int si = 0; si < 4; ++si)
#pragma unroll
            for (int cj = 0; cj < 4; ++cj) acc[si][cj] = 0.0f;
        for (int kc = 0; kc < CELL_DIM; kc += BK) {
            __syncthreads();
#pragma unroll
            for (int i = 0; i < 2; ++i) {
                int f = tid + i * 256;
                int c = f >> 3, k4 = (f & 7) << 2;
                float4 v = *(const float4*)(pc + (size_t)(jc + c) * CELL_DIM + kc + k4);
                ps[(k4 + 0) * PP + c] = v.x; ps[(k4 + 1) * PP + c] = v.y;
                ps[(k4 + 2) * PP + c] = v.z; ps[(k4 + 3) * PP + c] = v.w;
            }
            __syncthreads();
#pragma unroll
            for (int kk = 0; kk < BK; kk += 4) {
                float4 xv[4];
#pragma unroll
                for (int si = 0; si < 4; ++si)
                    xv[si] = *(const float4*)(&xs[(ty * 4 + si) * XP + kc + kk]);
#pragma unroll
                for (int kt = 0; kt < 4; ++kt) {
                    float4 pv = *(const float4*)(&ps[(kk + kt) * PP + tx * 4]);
#pragma unroll
                    for (int si = 0; si < 4; ++si) {
                        float xk = (kt == 0) ? xv[si].x : (kt == 1) ? xv[si].y :
                                   (kt == 2) ? xv[si].z : xv[si].w;
                        acc[si][0] = fmaf(xk, pv.x, acc[si][0]);
                        acc[si][1] = fmaf(xk, pv.y, acc[si][1]);
                        acc[si][2] = fmaf(xk, pv.z, acc[si][2]);
                        acc[si][3] = fmaf(xk, pv.w, acc[si][3]);
                    }
                }
            }
        }
#pragma unroll
        for (int si = 0; si < 4; ++si)
#pragma unroll
            for (int cj = 0; cj < 4; ++cj) {
                int idx = jc + tx * 4 + cj;
                if (acc[si][cj] > runv[si]) { runv[si] = acc[si][cj]; runi[si] = idx; }
            }
    }
    __syncthreads();
    float* rv = ps; int* ri = (int*)(ps + 1024);
#pragma unroll
    for (int si = 0; si < 4; ++si) {
        int s = ty * 4 + si;
        rv[s * 16 + tx] = runv[si]; ri[s * 16 + tx] = runi[si];
    }
    __syncthreads();
    if (tid < BM) {
        float bv = rv[tid * 16]; int bi = ri[tid * 16];
#pragma unroll
        for (int t = 1; t < 16; ++t) {
            float v = rv[tid * 16 + t]; int i = ri[tid * 16 + t];
            if (v > bv || (v == bv && i < bi)) { bv = v; bi = i; }
        }
        out[(size_t)blockIdx.x * BM + tid] = bi;
    }
}

extern "C" void kernel_launch(void* const* d_in, const int* in_sizes, int n_in,
                              void* d_out, int out_size, void* d_ws, size_t ws_size,
                              hipStream_t stream) {
    const float* x  = (const float*)d_in[0];   // (131072, 256) fp32
    const float* pc = (const float*)d_in[1];   // (2048, 256) fp32
    int* out = (int*)d_out;

    if (ws_size >= (size_t)WS_NEEDED) {
        char* ws = (char*)d_ws;
        int* c1 = (int*)(ws + WS_C1);
        int* c2 = (int*)(ws + WS_C2);
        int* l1 = (int*)(ws + WS_L1);
        int* l2 = (int*)(ws + WS_L2);
        _Float16* ph = (_Float16*)(ws + WS_PH);
        _Float16* pl = (_Float16*)(ws + WS_PL);
        prep_p<<<256, 256, 0, stream>>>(pc, ph, pl, c1, c2);
        pc_gemm1<<<N_STATES / 128, 512, 0, stream>>>(x, ph, out, c1, l1);
        pc_rescue2<<<256, 256, 0, stream>>>(x, ph, pl, c1, l1, out, c2, l2);
        rescue3<<<64, 256, 0, stream>>>(x, pc, c2, l2, out);
    } else {
        placecells_argmax_fp32<<<N_STATES / BM, 256, 0, stream>>>(x, pc, out);
    }
}